// Round 7
// baseline (1461.852 us; speedup 1.0000x reference)
//
#include <hip/hip_runtime.h>

// ---------- problem constants ----------
#define Bz   32
#define Pz   197
#define ENCz 768
#define EMBz 512
#define HIDz 512
#define ATTz 256
#define VOCz 32000
#define Tz   40

#define NBLK 224

typedef unsigned short ushort_t;
typedef __attribute__((ext_vector_type(8))) short frag_ab;     // 8 bf16 (4 VGPRs)
typedef __attribute__((ext_vector_type(4))) float frag_cd;     // 4 fp32 acc
typedef __attribute__((ext_vector_type(4))) ushort_t ushort4v; // 8B
typedef __attribute__((ext_vector_type(8))) ushort_t ushort8v; // 16B

#define MFMA16(a, b, c) __builtin_amdgcn_mfma_f32_16x16x32_bf16((a), (b), (c), 0, 0, 0)

__device__ __forceinline__ float b2f(ushort_t u) {
    return __uint_as_float(((unsigned)u) << 16);
}
__device__ __forceinline__ ushort_t f2bf(float f) {
    unsigned u = __float_as_uint(f);
    unsigned r = (u + 0x7fffu + ((u >> 16) & 1u)) >> 16;
    return (ushort_t)r;
}
__device__ __forceinline__ float sigf(float x) { return 1.f / (1.f + __expf(-x)); }
__device__ __forceinline__ float tanhfast(float x) { return 1.f - 2.f / (__expf(2.f * x) + 1.f); }

// ---------- uncached (agent-coherent) access helpers ----------
__device__ __forceinline__ void st_f32(float* p, float v) {
    __hip_atomic_store(p, v, __ATOMIC_RELAXED, __HIP_MEMORY_SCOPE_AGENT);
}
__device__ __forceinline__ float ld_f32(const float* p) {
    return __hip_atomic_load(p, __ATOMIC_RELAXED, __HIP_MEMORY_SCOPE_AGENT);
}
__device__ __forceinline__ void st_u32(unsigned* p, unsigned v) {
    __hip_atomic_store(p, v, __ATOMIC_RELAXED, __HIP_MEMORY_SCOPE_AGENT);
}
__device__ __forceinline__ unsigned ld_u32(const unsigned* p) {
    return __hip_atomic_load(p, __ATOMIC_RELAXED, __HIP_MEMORY_SCOPE_AGENT);
}
// 16B bf16 fragment via two 8B agent-scope loads (coherent, bypasses stale L2)
__device__ __forceinline__ frag_ab ldfrag(const ushort_t* p) {
    union { frag_ab f; unsigned long long q[2]; } u;
    u.q[0] = __hip_atomic_load((const unsigned long long*)p, __ATOMIC_RELAXED, __HIP_MEMORY_SCOPE_AGENT);
    u.q[1] = __hip_atomic_load((const unsigned long long*)(p + 4), __ATOMIC_RELAXED, __HIP_MEMORY_SCOPE_AGENT);
    return u.f;
}
// arrival: ensure this block's agent stores are at the coherence point, then set flag
__device__ __forceinline__ void arrive(unsigned* slot, unsigned v, int tid) {
    __syncthreads();                       // compiler drains vmcnt/lgkmcnt before s_barrier
    if (tid == 0) {
        asm volatile("s_waitcnt vmcnt(0)" ::: "memory");
        st_u32(slot, v);
    }
}

__global__ void k_binit(unsigned* f) {
    for (int i = threadIdx.x; i < 11264; i += 256) f[i] = 0u;
}

// ---------- fused prep: bf16 convert (blocks 0..2363), mean (2364..2459), encTb (2460..7835) ----------
__global__ __launch_bounds__(256) void k_prep(const float* __restrict__ enc, ushort_t* __restrict__ encB,
                                              float* __restrict__ meanE, ushort_t* __restrict__ encTb) {
    __shared__ float tile[32][33];
    const int bid = blockIdx.x, tid = threadIdx.x;
    if (bid < 2364) {
        size_t base = ((size_t)bid * 256 + tid) * 8;
        const float4* src = (const float4*)(enc + base);
        float4 a = src[0], b = src[1];
        ushort8v v;
        v[0] = f2bf(a.x); v[1] = f2bf(a.y); v[2] = f2bf(a.z); v[3] = f2bf(a.w);
        v[4] = f2bf(b.x); v[5] = f2bf(b.y); v[6] = f2bf(b.z); v[7] = f2bf(b.w);
        *(ushort8v*)(encB + base) = v;
    } else if (bid < 2460) {
        int e = (bid - 2364) * 256 + tid;
        int b = e / ENCz, d = e % ENCz;
        const float* p = enc + (size_t)b * Pz * ENCz + d;
        float s = 0.f;
        for (int i = 0; i < Pz; ++i) s += p[i * ENCz];
        meanE[e] = s * (1.f / (float)Pz);
    } else {
        int idx = bid - 2460;
        int d0 = (idx % 24) * 32; int rest = idx / 24;
        int p0 = (rest % 7) * 32; int b = rest / 7;
        int tx = tid & 31, ty = tid >> 5;
#pragma unroll
        for (int i = 0; i < 4; ++i) {
            int p = p0 + ty + i * 8;
            tile[ty + i * 8][tx] = (p < Pz) ? enc[((size_t)b * Pz + p) * ENCz + d0 + tx] : 0.f;
        }
        __syncthreads();
#pragma unroll
        for (int i = 0; i < 4; ++i) {
            int d = d0 + ty + i * 8, p = p0 + tx;
            if (p < 200) encTb[((size_t)b * ENCz + d) * 200 + p] = f2bf(tile[tx][ty + i * 8]);
        }
    }
}

// ---------- h0/c0 init (h0 bf16 lands in Abuf0 cols 768..1279) ----------
__global__ __launch_bounds__(256) void k_h0c0(const float* __restrict__ meanE,
                                              const float* __restrict__ W_inh, const float* __restrict__ b_inh,
                                              const float* __restrict__ W_inc, const float* __restrict__ b_inc,
                                              float* __restrict__ c_cur, ushort_t* __restrict__ Abuf) {
    __shared__ float msh[ENCz];
    int bid = blockIdx.x, tid = threadIdx.x;
    int b = bid >> 2, seg = bid & 3;             // seg0/1: h halves, seg2/3: c halves
    for (int i = tid; i < ENCz; i += 256) msh[i] = meanE[b * ENCz + i];
    __syncthreads();
    int col = (seg & 1) * 256 + tid;
    bool isc = (seg >> 1) != 0;
    const float* W = isc ? W_inc : W_inh;
    const float* bb = isc ? b_inc : b_inh;
    float a0 = 0.f, a1 = 0.f, a2 = 0.f, a3 = 0.f;
    for (int k = 0; k < ENCz; k += 4) {
        a0 += msh[k + 0] * W[(k + 0) * HIDz + col];
        a1 += msh[k + 1] * W[(k + 1) * HIDz + col];
        a2 += msh[k + 2] * W[(k + 2) * HIDz + col];
        a3 += msh[k + 3] * W[(k + 3) * HIDz + col];
    }
    float acc = a0 + a1 + a2 + a3 + bb[col];
    if (isc) c_cur[b * HIDz + col] = acc;
    else Abuf[b * 1280 + 768 + col] = f2bf(acc);
}

// ---------- embedding gather+convert ----------
__global__ __launch_bounds__(128) void k_gather(const int* __restrict__ captions, const float* __restrict__ emb,
                                                ushort_t* __restrict__ Xemb) {
    int row = blockIdx.x;                        // 0..1279 = t*32+b
    int t = row >> 5, b = row & 31;
    int cap = captions[b * 41 + t];
    float4 f = *(const float4*)(emb + (size_t)cap * EMBz + threadIdx.x * 4);
    ushort4v v; v[0] = f2bf(f.x); v[1] = f2bf(f.y); v[2] = f2bf(f.z); v[3] = f2bf(f.w);
    *(ushort4v*)(Xemb + (size_t)row * EMBz + threadIdx.x * 4) = v;
}

// ---------- fp32-in / bf16-out transpose ----------
__global__ __launch_bounds__(256) void k_transpose(const float* __restrict__ in, int R, int C,
                                                   ushort_t* __restrict__ out, int ldo, int koff) {
    __shared__ ushort_t tile[32][33];
    int c0 = blockIdx.x * 32, r0 = blockIdx.y * 32;
    int tx = threadIdx.x & 31, ty = threadIdx.x >> 5;    // ty 0..7
#pragma unroll
    for (int i = 0; i < 4; ++i) {
        int r = r0 + ty + i * 8;
        tile[ty + i * 8][tx] = f2bf(in[(size_t)r * C + c0 + tx]);
    }
    __syncthreads();
#pragma unroll
    for (int i = 0; i < 4; ++i) {
        int c = c0 + ty + i * 8;
        out[(size_t)c * ldo + koff + r0 + tx] = tile[tx][ty + i * 8];
    }
}

// ---------- MFMA GEMM ----------
// MODE 0: fp32 out (ldo), bias1+bias2;  MODE 1: bf16 out (ldo), bias1, row-guard
// MODE 2: fp32 out permuted for final preds (row m=t*32+b -> out[b][t][n]), XCD-swizzled grid
template <int MODE>
__global__ __launch_bounds__(256) void k_gemm(const ushort_t* __restrict__ A, int lda, int M,
                                              const ushort_t* __restrict__ BT, int K,
                                              const float* __restrict__ B1, const float* __restrict__ B2,
                                              void* __restrict__ out, int ldo) {
    __shared__ __align__(16) ushort_t As[128 * 64];
    __shared__ __align__(16) ushort_t Bs[128 * 64];
    const int tid = threadIdx.x;
    const int lane = tid & 63, w = tid >> 6;
    const int wm = w >> 1, wn = w & 1;
    int n0, m0;
    if (MODE == 2) {
        const int total = gridDim.x * gridDim.y;
        const int lin = blockIdx.y * gridDim.x + blockIdx.x;
        const int q = total >> 3, r = total - (q << 3);
        const int xcd = lin & 7, slot = lin >> 3;
        const int L = (xcd < r) ? xcd * (q + 1) + slot : r * (q + 1) + (xcd - r) * q + slot;
        const int nIdx = L / (int)gridDim.y;
        n0 = nIdx * 128; m0 = (L - nIdx * (int)gridDim.y) * 128;
    } else {
        n0 = blockIdx.x * 128; m0 = blockIdx.y * 128;
    }
    const int quad = lane >> 4, c16 = lane & 15;

    frag_cd acc[4][4];
#pragma unroll
    for (int i = 0; i < 4; ++i)
#pragma unroll
        for (int j = 0; j < 4; ++j) acc[i][j] = (frag_cd){0.f, 0.f, 0.f, 0.f};

    for (int k0 = 0; k0 < K; k0 += 64) {
#pragma unroll
        for (int it = 0; it < 4; ++it) {
            int c = tid + it * 256;              // chunk 0..1023
            int row = c >> 3, col8 = (c & 7) * 8;
            int gr = m0 + row; gr = gr < M ? gr : M - 1;
            *(frag_ab*)&As[row * 64 + col8] = *(const frag_ab*)&A[(size_t)gr * lda + k0 + col8];
            *(frag_ab*)&Bs[row * 64 + col8] = *(const frag_ab*)&BT[(size_t)(n0 + row) * K + k0 + col8];
        }
        __syncthreads();
#pragma unroll
        for (int kk = 0; kk < 64; kk += 32) {
            int kcol = kk + quad * 8;
            frag_ab af[4], bf[4];
#pragma unroll
            for (int i = 0; i < 4; ++i) af[i] = *(const frag_ab*)&As[(wm * 64 + i * 16 + c16) * 64 + kcol];
#pragma unroll
            for (int j = 0; j < 4; ++j) bf[j] = *(const frag_ab*)&Bs[(wn * 64 + j * 16 + c16) * 64 + kcol];
#pragma unroll
            for (int i = 0; i < 4; ++i)
#pragma unroll
                for (int j = 0; j < 4; ++j) acc[i][j] = MFMA16(af[i], bf[j], acc[i][j]);
        }
        __syncthreads();
    }

#pragma unroll
    for (int i = 0; i < 4; ++i) {
#pragma unroll
        for (int j = 0; j < 4; ++j) {
            int n = n0 + wn * 64 + j * 16 + c16;
            float bias = B1[n];
            if (B2 != nullptr) bias += B2[n];
#pragma unroll
            for (int r = 0; r < 4; ++r) {
                int m = m0 + wm * 64 + i * 16 + quad * 4 + r;
                float v = acc[i][j][r] + bias;
                if (MODE == 0) {
                    if (m < M) ((float*)out)[(size_t)m * ldo + n] = v;
                } else if (MODE == 1) {
                    if (m < M) ((ushort_t*)out)[(size_t)m * ldo + n] = f2bf(v);
                } else {
                    int b = m & 31, t = m >> 5;
                    ((float*)out)[(size_t)b * (Tz * VOCz) + (size_t)t * VOCz + n] = v;
                }
            }
        }
    }
}

// ---------- gate slice: gate[d0+d] = sigmoid(h . W_fbT-row) for d=0..95 (192 threads) ----------
__device__ __forceinline__ void gate_calc(const ushort_t* __restrict__ W_preT, const float* __restrict__ b_fb,
                                          const float* hsh, int d0, float* gate_out, int tid) {
    if (tid < 192) {
        const int d = tid >> 1, half = tid & 1;
        const ushort_t* wr = W_preT + (size_t)(256 + d0 + d) * 512 + half * 256;
        const float* hh = hsh + half * 256;
        float a0 = 0.f, a1 = 0.f;
        for (int k = 0; k < 256; k += 8) {
            ushort8v wv8 = *(const ushort8v*)&wr[k];
#pragma unroll
            for (int x = 0; x < 8; ++x) {
                float f = b2f(wv8[x]) * hh[k + x];
                if (x & 1) a1 += f; else a0 += f;
            }
        }
        float s = a0 + a1;
        s += __shfl_xor(s, 1, 64);
        if (half == 0) gate_out[d] = sigf(s + b_fb[d0 + d]);
    }
}

// ---------- awe dot: gawe bf16 into dst[d0..d0+95] from LDS enc slice ----------
__device__ __forceinline__ void awe_dot(const ushort_t* encS, const float* gate_l, const float* alpha_l,
                                        ushort_t* dst, int tid) {
    if (tid < 192) {
        const int d = tid >> 1, h = tid & 1;
        const int c0 = h ? 13 : 0, c1 = h ? 25 : 13;
        float s = 0.f;
        for (int c = c0; c < c1; ++c) {
            ushort8v v = *(const ushort8v*)&encS[d * 200 + c * 8];
#pragma unroll
            for (int jj = 0; jj < 8; ++jj) s += b2f(v[jj]) * alpha_l[c * 8 + jj];
        }
        s += __shfl_xor(s, 1, 64);
        float gs = s * gate_l[d];
        unsigned pk = f2bf(gs);
        unsigned nb = __shfl_down(pk, 2, 64);
        if ((tid & 3) == 0) st_u32((unsigned*)(dst + d), pk | (nb << 16));
    }
}

// ---------- persistent recurrence kernel: dataflow sync, 3 hops/step ----------
// Roles: g 0..127:   AWE(task g) + S3(cols g*4); 128..191: AWE(task g) + AWE(192+(g-128));
//        192..223:  ESET(b=g-192): att2 (redundant, W_preT from L2) + e + softmax -> alpha.
// flags: flagS[128] (h ready), flagA[192] (gawe ready), flagE[32] (alpha ready). Monotonic t+1.
__global__ __launch_bounds__(256, 1) void k_recur(
    const ushort_t* __restrict__ att1, const ushort_t* __restrict__ encTb,
    const ushort_t* __restrict__ W_preT, const float* __restrict__ b_da,
    const float* __restrict__ b_fb, const float* __restrict__ w_fa,
    const float* __restrict__ b_fa, const ushort_t* __restrict__ WgT,
    const float* __restrict__ Xih, const float* __restrict__ c0,
    ushort_t* __restrict__ Abuf, float* __restrict__ alpha_buf,
    ushort_t* __restrict__ Hall, unsigned* __restrict__ barflags)
{
    __shared__ __align__(16) char smem[126208];
    float* scratch = (float*)smem;                             // 2048 floats = 8,192 B
    char* R = smem + 8192;                                     // role-specific region

    unsigned* flagS = barflags;                                // 128 x 32 u32
    unsigned* flagA = barflags + 4096;                         // 192 x 32 u32
    unsigned* flagE = barflags + 10240;                        // 32 x 32 u32

    const int g = (int)blockIdx.x;
    const int tid = (int)threadIdx.x;
    const int lane = tid & 63, wv = tid >> 6;
    const int quad = lane >> 4, c16 = lane & 15;

    const bool isS3 = (g < 128);
    const bool isE  = (g >= 192);
    const bool dual = (g >= 128 && g < 192);
    const int j0 = g << 2;                                     // S3 cols (g<128)
    const int task0 = g;                                       // awe task (g<192)
    const int task1 = dual ? 192 + (g - 128) : 0;
    const int b0 = task0 >> 3, d0 = (task0 & 7) * 96;
    const int b1 = task1 >> 3, d1 = (task1 & 7) * 96;
    const int eb = g - 192;

    ushort_t (*Wl)[1288] = (ushort_t(*)[1288])R;               // S3: 41,216 B
    ushort_t* enc0  = isS3 ? (ushort_t*)(R + 41216) : (ushort_t*)R;  // [96][200] = 38,400 B
    ushort_t* enc1  = (ushort_t*)(R + 38400);                  // dual blocks only
    ushort_t* att1L = (ushort_t*)R;                            // ESET: [197][264] = 104,016 B

    // ---- one-time staging ----
    if (isS3) {                                                // Wl: 16 Wg cols
        int r = tid >> 4, ch = tid & 15;
        int coln = ((r >> 2) << 9) + j0 + (r & 3);
        const ushort_t* src = WgT + (size_t)coln * 1280 + ch * 80;
        ushort_t* dst = &Wl[r][ch * 80];
#pragma unroll
        for (int i = 0; i < 10; ++i)
            *(ushort8v*)(dst + i * 8) = *(const ushort8v*)(src + i * 8);
    }
    if (!isE) {
        const ushort_t* src = encTb + ((size_t)(b0 * 768 + (task0 & 7) * 96)) * 200;
        for (int i = 0; i < 10; ++i) {
            int c = tid + i * 256;
            if (c < 2400) *(ushort8v*)&enc0[c * 8] = *(const ushort8v*)&src[c * 8];
        }
        if (dual) {
            const ushort_t* src1 = encTb + ((size_t)(b1 * 768 + (task1 & 7) * 96)) * 200;
            for (int i = 0; i < 10; ++i) {
                int c = tid + i * 256;
                if (c < 2400) *(ushort8v*)&enc1[c * 8] = *(const ushort8v*)&src1[c * 8];
            }
        }
    } else {
        for (int i = 0; i < 25; ++i) {
            int c = tid + i * 256;                             // 6304 chunks of 16B
            if (c < 6304) {
                int p = c >> 5, off = (c & 31) * 8;
                *(ushort8v*)&att1L[p * 264 + off] = *(const ushort8v*)&att1[((size_t)(eb * Pz + p)) * 256 + off];
            }
        }
    }
    float creg = 0.f;
    if (isS3 && tid < 128) creg = c0[(tid >> 2) * HIDz + j0 + (tid & 3)];
    __syncthreads();

    for (int t = 0; t < Tz; ++t) {
        ushort_t* Ab_r = Abuf + (size_t)(t & 1) * 40960;
        ushort_t* Ab_w = Abuf + (size_t)((t + 1) & 1) * 40960;
        const unsigned epoch = (unsigned)(t + 1);

        if (isE) {
            // ===== ESET: wait h -> att2 -> e -> softmax -> alpha =====
            if (t) {
                if (tid < 128) while (ld_u32(&flagS[tid << 5]) < (unsigned)t) __builtin_amdgcn_s_sleep(1);
                __syncthreads();
            }
            if (tid < 64) {                                    // h[eb] -> fp32 LDS
                frag_ab v = ldfrag(Ab_r + eb * 1280 + 768 + tid * 8);
#pragma unroll
                for (int i = 0; i < 8; ++i) scratch[tid * 8 + i] = b2f((ushort_t)v[i]);
            }
            __syncthreads();
            {                                                  // att2[tid] via W_preT row (L2-cached)
                const ushort_t* wr = W_preT + (size_t)tid * 512;
                float a0 = 0.f, a1 = 0.f, a2 = 0.f, a3 = 0.f;
                for (int k = 0; k < 512; k += 16) {
                    ushort8v w0 = *(const ushort8v*)&wr[k];
                    ushort8v w1 = *(const ushort8v*)&wr[k + 8];
#pragma unroll
                    for (int x = 0; x < 8; ++x) {
                        float f0 = b2f(w0[x]) * scratch[k + x];
                        float f1 = b2f(w1[x]) * scratch[k + 8 + x];
                        if (x & 1) { a1 += f0; a3 += f1; } else { a0 += f0; a2 += f1; }
                    }
                }
                scratch[512 + tid] = (a0 + a1) + (a2 + a3) + b_da[tid];
                scratch[768 + tid] = w_fa[tid];
            }
            __syncthreads();
            float ev = -3.0e38f;
            if (tid < Pz) {
                const ushort_t* ar = att1L + tid * 264;
                float s = 0.f;
#pragma unroll
                for (int j8 = 0; j8 < 256; j8 += 8) {
                    ushort8v v = *(const ushort8v*)&ar[j8];
#pragma unroll
                    for (int jj = 0; jj < 8; ++jj)
                        s += fmaxf(b2f(v[jj]) + scratch[512 + j8 + jj], 0.f) * scratch[768 + j8 + jj];
                }
                ev = s + b_fa[0];
            }
            float mv = ev;
            for (int o = 32; o; o >>= 1) mv = fmaxf(mv, __shfl_down(mv, o, 64));
            if (lane == 0) scratch[1024 + wv] = mv;
            __syncthreads();
            const float mx = fmaxf(fmaxf(scratch[1024], scratch[1025]), fmaxf(scratch[1026], scratch[1027]));
            float ex = (tid < Pz) ? __expf(ev - mx) : 0.f;
            float sv = ex;
            for (int o = 32; o; o >>= 1) sv += __shfl_down(sv, o, 64);
            if (lane == 0) scratch[1028 + wv] = sv;
            __syncthreads();
            const float inv = 1.f / (scratch[1028] + scratch[1029] + scratch[1030] + scratch[1031]);
            if (tid < 200) st_f32(&alpha_buf[eb * 200 + tid], ex * inv);
            arrive(&flagE[eb << 5], epoch, tid);
        } else {
            // ===== AWE: wait h -> gate(s) -> wait alpha -> awe dot(s) =====
            if (t) {
                if (tid < 128) while (ld_u32(&flagS[tid << 5]) < (unsigned)t) __builtin_amdgcn_s_sleep(1);
                __syncthreads();
            }
            if (tid < 64) {                                    // h[b0] -> fp32 LDS [0..512)
                frag_ab v = ldfrag(Ab_r + b0 * 1280 + 768 + tid * 8);
#pragma unroll
                for (int i = 0; i < 8; ++i) scratch[tid * 8 + i] = b2f((ushort_t)v[i]);
            }
            if (dual && tid >= 64 && tid < 128) {              // h[b1] -> [512..1024)
                int tt = tid - 64;
                frag_ab v = ldfrag(Ab_r + b1 * 1280 + 768 + tt * 8);
#pragma unroll
                for (int i = 0; i < 8; ++i) scratch[512 + tt * 8 + i] = b2f((ushort_t)v[i]);
            }
            __syncthreads();
            gate_calc(W_preT, b_fb, scratch, d0, scratch + 1024, tid);
            if (dual) gate_calc(W_preT, b_fb, scratch + 512, d1, scratch + 1120, tid);
            __syncthreads();
            if (tid == 0)  while (ld_u32(&flagE[b0 << 5]) < epoch) __builtin_amdgcn_s_sleep(1);
            if (dual && tid == 32) while (ld_u32(&flagE[b1 << 5]) < epoch) __builtin_amdgcn_s_sleep(1);
            __syncthreads();
            if (tid < 200) scratch[1280 + tid] = ld_f32(&alpha_buf[b0 * 200 + tid]);
            __syncthreads();
            awe_dot(enc0, scratch + 1024, scratch + 1280, Ab_r + b0 * 1280 + d0, tid);
            if (dual) {
                __syncthreads();
                if (tid < 200) scratch[1280 + tid] = ld_f32(&alpha_buf[b1 * 200 + tid]);
                __syncthreads();
                awe_dot(enc1, scratch + 1120, scratch + 1280, Ab_r + b1 * 1280 + d1, tid);
            }
            arrive(&flagA[g << 5], epoch, tid);
        }

        // ===== S3: wait gawe -> gates GEMM + LSTM -> h =====
        if (isS3) {
            if (tid < 192) while (ld_u32(&flagA[tid << 5]) < epoch) __builtin_amdgcn_s_sleep(1);
            __syncthreads();
            frag_cd p0 = (frag_cd){0.f, 0.f, 0.f, 0.f};
            frag_cd p1 = (frag_cd){0.f, 0.f, 0.f, 0.f};
            const ushort_t* Ar0 = Ab_r + (size_t)c16 * 1280 + wv * 320 + quad * 8;
            const ushort_t* Ar1 = Ar0 + 16 * 1280;
            const ushort_t* Wr = &Wl[c16][wv * 320 + quad * 8];
#pragma unroll
            for (int ks = 0; ks < 10; ++ks) {
                frag_ab bfr = *(const frag_ab*)(Wr + ks * 32);
                p0 = MFMA16(ldfrag(Ar0 + ks * 32), bfr, p0);
                p1 = MFMA16(ldfrag(Ar1 + ks * 32), bfr, p1);
            }
#pragma unroll
            for (int r = 0; r < 4; ++r) {
                scratch[wv * 512 + (quad * 4 + r) * 16 + c16] = p0[r];
                scratch[wv * 512 + 256 + (quad * 4 + r) * 16 + c16] = p1[r];
            }
            __syncthreads();
            float s0, s1;
            {
                const int mr = tid >> 4, col = tid & 15;
                const int base = mr * 16 + col;
                const int xcol = ((col >> 2) << 9) + j0 + (col & 3);
                s0 = scratch[base] + scratch[512 + base] + scratch[1024 + base] + scratch[1536 + base]
                   + Xih[(size_t)t * 65536 + mr * 2048 + xcol];
                s1 = scratch[256 + base] + scratch[768 + base] + scratch[1280 + base] + scratch[1792 + base]
                   + Xih[(size_t)t * 65536 + (16 + mr) * 2048 + xcol];
            }
            __syncthreads();
            scratch[tid] = s0;
            scratch[256 + tid] = s1;
            __syncthreads();
            if (tid < 128) {
                const int bl = tid >> 2, jj = tid & 3, j = j0 + jj;
                const float iv = scratch[bl * 16 + jj], fv = scratch[bl * 16 + 4 + jj];
                const float gv = scratch[bl * 16 + 8 + jj], ov = scratch[bl * 16 + 12 + jj];
                const float cn = sigf(fv) * creg + sigf(iv) * tanhfast(gv);
                creg = cn;
                const float hn = sigf(ov) * tanhfast(cn);
                const ushort_t hb = f2bf(hn);
                Hall[((size_t)t * 32 + bl) * HIDz + j] = hb;
                unsigned pk = hb;
                unsigned nb = __shfl_down(pk, 1, 64);
                if ((tid & 1) == 0)
                    st_u32((unsigned*)(Ab_w + bl * 1280 + 768 + j), pk | (nb << 16));
            }
            arrive(&flagS[g << 5], epoch, tid);
        }
    }
}

// ---------- launcher ----------
extern "C" void kernel_launch(void* const* d_in, const int* in_sizes, int n_in,
                              void* d_out, int out_size, void* d_ws, size_t ws_size,
                              hipStream_t stream) {
    const float* enc   = (const float*)d_in[0];
    const int*   caps  = (const int*)d_in[1];
    const float* emb   = (const float*)d_in[2];
    const float* W_ea  = (const float*)d_in[3];
    const float* b_ea  = (const float*)d_in[4];
    const float* W_da  = (const float*)d_in[5];
    const float* b_da  = (const float*)d_in[6];
    const float* w_fa  = (const float*)d_in[7];
    const float* b_fa  = (const float*)d_in[8];
    const float* W_inh = (const float*)d_in[9];
    const float* b_inh = (const float*)d_in[10];
    const float* W_inc = (const float*)d_in[11];
    const float* b_inc = (const float*)d_in[12];
    const float* W_fb  = (const float*)d_in[13];
    const float* b_fb  = (const float*)d_in[14];
    const float* W_ih  = (const float*)d_in[15];
    const float* b_ih  = (const float*)d_in[16];
    const float* W_hh  = (const float*)d_in[17];
    const float* b_hh  = (const float*)d_in[18];
    const float* W_out = (const float*)d_in[19];
    const float* b_out = (const float*)d_in[20];

    char* ws = (char*)d_ws;
    ushort_t* att1     = (ushort_t*)(ws + 0);            // 6304x256 bf16     -> 3,227,648
    ushort_t* Xemb     = (ushort_t*)(ws + 3227648);      // 1280x512 bf16     -> 4,538,368
    ushort_t* encB     = (ushort_t*)(ws + 4538368);      // 6304x768 bf16     -> 14,221,312
    float*    Xih      = (float*)(ws + 14221312);        // 40x32x2048 fp32   -> 24,707,072
    float*    meanE    = (float*)(ws + 24707072);        // 32x768 fp32       -> 24,805,376
    float*    c_cur    = (float*)(ws + 24805376);        // 32x512 fp32       -> 24,870,912
    ushort_t* Abuf     = (ushort_t*)(ws + 24870912);     // 2 x 32x1280 bf16  -> 25,034,752
    float*    alpha_buf= (float*)(ws + 25165824);        // 32x200 fp32       -> 25,191,424
    ushort_t* Hall     = (ushort_t*)(ws + 25191424);     // 1280x512 bf16     -> 26,502,144
    ushort_t* WgT      = (ushort_t*)(ws + 26502144);     // 2048x1280 bf16    -> 31,745,024
    ushort_t* W_preT   = (ushort_t*)(ws + 31745024);     // 1024x512 bf16     -> 32,793,600
    ushort_t* W_eaT    = (ushort_t*)(ws + 32793600);     // 256x768 bf16      -> 33,186,816
    ushort_t* W_ihxT   = (ushort_t*)(ws + 33186816);     // 2048x512 bf16     -> 35,283,968
    ushort_t* W_outT   = (ushort_t*)(ws + 35283968);     // 32000x512 bf16    -> 68,051,968
    ushort_t* encTb    = (ushort_t*)(ws + 68051968);     // 32x768x200 bf16   -> 77,882,368
    unsigned* barflags = (unsigned*)(ws + 77882368);     // 11264 u32 = 45 KB

    // precompute (order-independent, single stream)
    k_binit<<<1, 256, 0, stream>>>(barflags);
    k_prep<<<7836, 256, 0, stream>>>(enc, encB, meanE, encTb);
    k_h0c0<<<128, 256, 0, stream>>>(meanE, W_inh, b_inh, W_inc, b_inc, c_cur, Abuf);
    k_gather<<<1280, 128, 0, stream>>>(caps, emb, Xemb);
    k_transpose<<<dim3(8, 24), 256, 0, stream>>>(W_ea, 768, 256, W_eaT, 768, 0);
    k_transpose<<<dim3(64, 16), 256, 0, stream>>>(W_ih, 512, 2048, W_ihxT, 512, 0);
    k_transpose<<<dim3(64, 24), 256, 0, stream>>>(W_ih + 512 * 2048, 768, 2048, WgT, 1280, 0);
    k_transpose<<<dim3(64, 16), 256, 0, stream>>>(W_hh, 512, 2048, WgT, 1280, 768);
    k_transpose<<<dim3(8, 16), 256, 0, stream>>>(W_da, 512, 256, W_preT, 512, 0);
    k_transpose<<<dim3(24, 16), 256, 0, stream>>>(W_fb, 512, 768, W_preT + 256 * 512, 512, 0);
    k_transpose<<<dim3(1000, 16), 256, 0, stream>>>(W_out, 512, 32000, W_outT, 512, 0);

    // att1 = enc @ W_ea + b_ea   (bf16 out, row-major [b*197+p][256])
    k_gemm<1><<<dim3(2, 50), 256, 0, stream>>>(encB, 768, 6304, W_eaT, 768, b_ea, nullptr, att1, 256);
    // Xih = Xemb @ W_ih[:512] + b_ih + b_hh  (fp32 out)
    k_gemm<0><<<dim3(16, 10), 256, 0, stream>>>(Xemb, 512, 1280, W_ihxT, 512, b_ih, b_hh, Xih, 2048);

    // full 40-step recurrence: one persistent kernel, dataflow flags (3 hops/step)
    hipLaunchKernelGGL(k_recur, dim3(NBLK), dim3(256), 0, stream,
                       att1, encTb, W_preT, b_da, b_fb, w_fa, b_fa, WgT, Xih,
                       c_cur, Abuf, alpha_buf, Hall, barflags);

    // preds = Hall @ W_out + b_out -> d_out (B,T,V) fp32
    k_gemm<2><<<dim3(250, 10), 256, 0, stream>>>(Hall, 512, 1280, W_outT, 512, b_out, nullptr, d_out, VOCz);
}